// Round 8
// baseline (143.599 us; speedup 1.0000x reference)
//
#include <hip/hip_runtime.h>
#include <hip/hip_bf16.h>
#include <math.h>

#define HIDDEN 2048
#define NEXP   64
#define NTOK   16384
#define NTGF   512

typedef __attribute__((ext_vector_type(8))) _Float16 f16x8;  // 8 f16 = 4 VGPR (MFMA A/B frag)
typedef __attribute__((ext_vector_type(4))) float   f32x4;   // MFMA C/D frag

// 2-way fp16 RNE split: x = h + l + O(2^-22). Residual exact (Sterbenz), l may be subnormal (ok).
__device__ __forceinline__ void split2_f16(float4 f0, float4 f1, f16x8& h, f16x8& l) {
    float e[8] = {f0.x, f0.y, f0.z, f0.w, f1.x, f1.y, f1.z, f1.w};
    f16x8 hv, lv;
#pragma unroll
    for (int i = 0; i < 8; ++i) {
        _Float16 hh = (_Float16)e[i];        // v_cvt_f16_f32 (RNE)
        float r = e[i] - (float)hh;          // exact residual
        hv[i] = hh;
        lv[i] = (_Float16)r;
    }
    h = hv; l = lv;
}

// ---------------- prep: w [64][2048] fp32 -> wh/wl f16x8 slots, pre-swizzled ----------------
// Slot (c, e, kgp) holds w[e][c*64 + (kgp^(e&7))*8 .. +7]; flat = c*512 + e*8 + kgp.
// Linear LDS image for global_load_lds; XOR keeps B ds_read_b128 at 2-way (free).
// Also zeroes the 128 split-K fixup counters every launch (graph-replay safe).
__global__ __launch_bounds__(256) void prep_kernel(
    const float* __restrict__ gw, uint4* __restrict__ wh, uint4* __restrict__ wl,
    unsigned* __restrict__ cnt)
{
    const int gid = blockIdx.x * 256 + threadIdx.x;   // 0..16383
    if (cnt && gid < 128) cnt[gid] = 0u;
    const int c   = gid >> 9;
    const int e   = (gid >> 3) & 63;
    const int kgp = gid & 7;
    const int kg  = kgp ^ (e & 7);
    const float* src = gw + (size_t)e * HIDDEN + c * 64 + kg * 8;
    float4 s0 = *(const float4*)src;
    float4 s1 = *(const float4*)(src + 4);
    f16x8 h, l;
    split2_f16(s0, s1, h, l);
    wh[gid] = __builtin_bit_cast(uint4, h);
    wl[gid] = __builtin_bit_cast(uint4, l);
}

// ---------------- gemm body: R0's split-K MFMA GEMM, verbatim (45.2 us config) ----------------
// Wave: 32 tokens (2 m-reps) x 64 experts. Per ks-step: 8 ds_read_b128 feed 24 MFMAs.
// Double-buffer: stage chunk c+1 at start of chunk c; one barrier per 64-k chunk.
#define STAGE(cg, bo)                                                                     \
    _Pragma("unroll")                                                                     \
    for (int rr = 0; rr < 2; ++rr) {                                                      \
        const int s = rr * 256 + tid;                                                     \
        __builtin_amdgcn_global_load_lds(                                                 \
            (const __attribute__((address_space(1))) void*)(wh + (size_t)(cg) * 512 + s), \
            (__attribute__((address_space(3))) void*)&Bs[(bo) + s], 16, 0, 0);            \
        __builtin_amdgcn_global_load_lds(                                                 \
            (const __attribute__((address_space(1))) void*)(wl + (size_t)(cg) * 512 + s), \
            (__attribute__((address_space(3))) void*)&Bs[(bo) + 512 + s], 16, 0, 0);      \
    }

template<int KLEN>
__device__ __forceinline__ void gemm_body(
    const float* __restrict__ x, const uint4* __restrict__ wh, const uint4* __restrict__ wl,
    float* __restrict__ part, uint4* __restrict__ Bs, const int tid, const int bx, const int kg)
{
    const int l   = tid & 63;
    const int wv  = tid >> 6;
    const int kbase = kg * KLEN;
    const int nch   = KLEN >> 6;     // 64-k chunks
    const int cg0   = kbase >> 6;
    const int t0    = bx * 128 + wv * 32;

    // A: lane l -> rows t0+(l&15), t0+16+(l&15); k-group (l>>4)*8 within each 32-k step
    const float4* xp0 = (const float4*)(x + (size_t)(t0 + (l & 15)) * HIDDEN + kbase) + ((l >> 4) * 2);
    const float4* xp1 = (const float4*)(x + (size_t)(t0 + 16 + (l & 15)) * HIDDEN + kbase) + ((l >> 4) * 2);

    // B slot base: e=(l&15)+16eg, kgp=((ks<<2)|(l>>4))^(l&7); ks XOR'd at use
    const int lb = ((l & 15) << 3) | ((l >> 4) ^ (l & 7));

    f32x4 acc1[2][4], acc2[2][4];    // [m-rep][eg]
#pragma unroll
    for (int r = 0; r < 2; ++r)
#pragma unroll
        for (int eg = 0; eg < 4; ++eg) {
            acc1[r][eg] = (f32x4){0.f, 0.f, 0.f, 0.f};
            acc2[r][eg] = (f32x4){0.f, 0.f, 0.f, 0.f};
        }

    // prologue: stage chunk 0 -> buf 0; load chunk 0's A
    STAGE(cg0, 0)
    float4 a00 = xp0[0], a01 = xp0[1], a02 = xp0[8], a03 = xp0[9];
    float4 a10 = xp1[0], a11 = xp1[1], a12 = xp1[8], a13 = xp1[9];
    __syncthreads();

    for (int c = 0; c < nch; ++c) {
        const int buf = c & 1;
        float4 n00 = a00, n01 = a01, n02 = a02, n03 = a03;
        float4 n10 = a10, n11 = a11, n12 = a12, n13 = a13;
        if (c + 1 < nch) {
            STAGE(cg0 + c + 1, (buf ^ 1) * 1024)
            const int fb = (c + 1) * 16;
            n00 = xp0[fb + 0]; n01 = xp0[fb + 1]; n02 = xp0[fb + 8]; n03 = xp0[fb + 9];
            n10 = xp1[fb + 0]; n11 = xp1[fb + 1]; n12 = xp1[fb + 8]; n13 = xp1[fb + 9];
        }

#pragma unroll
        for (int ks = 0; ks < 2; ++ks) {
            f16x8 ah0, al0, ah1, al1;
            split2_f16(ks ? a02 : a00, ks ? a03 : a01, ah0, al0);
            split2_f16(ks ? a12 : a10, ks ? a13 : a11, ah1, al1);
            const int ib = buf * 1024 + (lb ^ (ks << 2));
#pragma unroll
            for (int eg = 0; eg < 4; ++eg) {
                f16x8 bh = __builtin_bit_cast(f16x8, Bs[ib + eg * 128]);
                f16x8 bl = __builtin_bit_cast(f16x8, Bs[ib + 512 + eg * 128]);
                acc1[0][eg] = __builtin_amdgcn_mfma_f32_16x16x32_f16(ah0, bh, acc1[0][eg], 0, 0, 0); // hh
                acc2[0][eg] = __builtin_amdgcn_mfma_f32_16x16x32_f16(ah0, bl, acc2[0][eg], 0, 0, 0); // hl
                acc2[0][eg] = __builtin_amdgcn_mfma_f32_16x16x32_f16(al0, bh, acc2[0][eg], 0, 0, 0); // lh
                acc1[1][eg] = __builtin_amdgcn_mfma_f32_16x16x32_f16(ah1, bh, acc1[1][eg], 0, 0, 0);
                acc2[1][eg] = __builtin_amdgcn_mfma_f32_16x16x32_f16(ah1, bl, acc2[1][eg], 0, 0, 0);
                acc2[1][eg] = __builtin_amdgcn_mfma_f32_16x16x32_f16(al1, bh, acc2[1][eg], 0, 0, 0);
            }
        }
        a00 = n00; a01 = n01; a02 = n02; a03 = n03;
        a10 = n10; a11 = n11; a12 = n12; a13 = n13;
        __syncthreads();
    }

    // store: m-rep r, reg (eg,i) -> token t0 + r*16 + (l>>4)*4 + i, expert eg*16 + (l&15)
    float* pp = part + ((size_t)kg * NTOK + t0) * NEXP;
#pragma unroll
    for (int r = 0; r < 2; ++r)
#pragma unroll
        for (int eg = 0; eg < 4; ++eg)
#pragma unroll
            for (int i = 0; i < 4; ++i)
                pp[(size_t)(r * 16 + (l >> 4) * 4 + i) * NEXP + eg * 16 + (l & 15)] =
                    acc1[r][eg][i] + acc2[r][eg][i];
}

// ---------------- finish body: reduce partials + bias + top-2 + weights + mask (R1 verbatim) ----
__device__ __forceinline__ void finish_body(
    const float* __restrict__ part, const float* __restrict__ bias_g,
    float* __restrict__ logits, float* __restrict__ weights, float* __restrict__ idxf,
    float* __restrict__ mask, const int KS, const int tid, const int bm0,
    float (*Ls)[65], int* selA, int* selB)
{
    const int tn = tid & 15;         // expert group of 4
    const int tm = tid >> 4;         // 16 row-groups; each owns rows tm and tm+16

    float4 acc[2];
#pragma unroll
    for (int i = 0; i < 2; ++i) acc[i] = make_float4(0.f, 0.f, 0.f, 0.f);

    for (int kg = 0; kg < KS; ++kg) {
        const float* pb = part + ((size_t)kg * NTOK + bm0) * NEXP;
#pragma unroll
        for (int i = 0; i < 2; ++i) {
            float4 v = *(const float4*)&pb[(tm + 16 * i) * NEXP + 4 * tn];
            acc[i].x += v.x; acc[i].y += v.y; acc[i].z += v.z; acc[i].w += v.w;
        }
    }

    const float4 bv = *(const float4*)&bias_g[4 * tn];
#pragma unroll
    for (int i = 0; i < 2; ++i) {
        const int m = tm + 16 * i;
        float4 v;
        v.x = acc[i].x + bv.x;
        v.y = acc[i].y + bv.y;
        v.z = acc[i].z + bv.z;
        v.w = acc[i].w + bv.w;
        *(float4*)&logits[(size_t)(bm0 + m) * NEXP + 4 * tn] = v;
        Ls[m][4 * tn + 0] = v.x;
        Ls[m][4 * tn + 1] = v.y;
        Ls[m][4 * tn + 2] = v.z;
        Ls[m][4 * tn + 3] = v.w;
    }
    __syncthreads();

    if (tid < 32) {
        const int t = tid;
        float best = -1e30f, second = -1e30f;
        int bi = 0, si = 0;
#pragma unroll
        for (int e = 0; e < NEXP; ++e) {
            float v = Ls[t][e];
            if (v > best)        { second = best; si = bi; best = v; bi = e; }
            else if (v > second) { second = v; si = e; }
        }
        float r  = __expf(second - best);   // softmax denom cancels in the ratio
        float w0 = 1.f / (1.f + r);
        float w1 = r / (1.f + r);
        const int tgl = bm0 + t;
        weights[2 * tgl + 0] = w0;
        weights[2 * tgl + 1] = w1;
        idxf[2 * tgl + 0] = (float)bi;
        idxf[2 * tgl + 1] = (float)si;
        selA[t] = bi;
        selB[t] = si;
    }
    __syncthreads();

    // mask: 64 experts x 2 k x 32 tokens; thread -> 4 (e,k) pairs x 4 tokens (float4)
    const int t8 = tid & 7;          // token group of 4 (8 groups = 32 tokens)
    const int pg = tid >> 3;         // 0..31, 4 pairs each
    const int b0 = 4 * t8;
    int sA0 = selA[b0+0], sA1 = selA[b0+1], sA2 = selA[b0+2], sA3 = selA[b0+3];
    int sB0 = selB[b0+0], sB1 = selB[b0+1], sB2 = selB[b0+2], sB3 = selB[b0+3];
#pragma unroll
    for (int p = 0; p < 4; ++p) {
        const int pair = pg * 4 + p;
        const int e = pair >> 1;
        const int k = pair & 1;
        const int a0 = k ? sB0 : sA0, a1 = k ? sB1 : sA1, a2 = k ? sB2 : sA2, a3 = k ? sB3 : sA3;
        float4 v;
        v.x = (a0 == e) ? 1.f : 0.f;
        v.y = (a1 == e) ? 1.f : 0.f;
        v.z = (a2 == e) ? 1.f : 0.f;
        v.w = (a3 == e) ? 1.f : 0.f;
        *(float4*)&mask[((size_t)e * 2 + k) * NTOK + bm0 + b0] = v;
    }
}

// ---------------- gemm + split-K fixup: last kg-block per token tile runs the finish ----------
// R7's cooperative launch silently no-opped under graph capture (logits stayed zero).
// Same effect via device-scope atomics: after partial stores, threadfence+barrier, tid0 does
// agent-scope atomicAdd on cnt[bx]; the 4th arriver (old==3) acquires and finishes 128 tokens.
// No spin-waits -> no deadlock; summation order identical to the two-kernel version.
__global__ __launch_bounds__(256, 2) void gemm_fixup_kernel(
    const float* __restrict__ x, const uint4* __restrict__ wh, const uint4* __restrict__ wl,
    const float* __restrict__ bias_g, float* __restrict__ part, unsigned* __restrict__ cnt,
    float* __restrict__ logits, float* __restrict__ weights, float* __restrict__ idxf,
    float* __restrict__ mask)
{
    __shared__ uint4 Bs[2 * 1024];   // 32 KB gemm staging
    __shared__ float Ls[32][65];     // finish tile
    __shared__ int selA[32], selB[32];
    __shared__ int lastFlag;

    const int tid = threadIdx.x;
    const int bx  = blockIdx.x;      // 0..127 token tile
    const int kg  = blockIdx.y;      // 0..3 K slice

    gemm_body<512>(x, wh, wl, part, Bs, tid, bx, kg);

    // release this block's partials device-wide, then count arrivals for this token tile
    __threadfence();
    __syncthreads();
    if (tid == 0) {
        unsigned old = __hip_atomic_fetch_add(&cnt[bx], 1u, __ATOMIC_ACQ_REL,
                                              __HIP_MEMORY_SCOPE_AGENT);
        lastFlag = (old == 3u);
    }
    __syncthreads();

    if (lastFlag) {
        __threadfence();             // acquire: invalidate stale cached lines before remote reads
        for (int g = 0; g < 4; ++g) {
            finish_body(part, bias_g, logits, weights, idxf, mask, 4, tid,
                        bx * 128 + g * 32, Ls, selA, selB);
            __syncthreads();
        }
    }
}

// ---------------- standalone kernels (fallback paths) ----------------
template<int KLEN>
__global__ __launch_bounds__(256, 2) void gemm_kernel(
    const float* __restrict__ x, const uint4* __restrict__ wh, const uint4* __restrict__ wl,
    float* __restrict__ part)
{
    __shared__ uint4 Bs[2 * 1024];
    gemm_body<KLEN>(x, wh, wl, part, Bs, threadIdx.x, blockIdx.x, blockIdx.y);
}

__global__ __launch_bounds__(256) void finish_kernel(
    const float* __restrict__ part, const float* __restrict__ bias_g,
    float* __restrict__ logits, float* __restrict__ weights, float* __restrict__ idxf,
    float* __restrict__ mask, int KS)
{
    __shared__ float Ls[32][65];
    __shared__ int selA[32], selB[32];
    finish_body(part, bias_g, logits, weights, idxf, mask, KS, threadIdx.x, blockIdx.x * 32,
                Ls, selA, selB);
}

extern "C" void kernel_launch(void* const* d_in, const int* in_sizes, int n_in,
                              void* d_out, int out_size, void* d_ws, size_t ws_size,
                              hipStream_t stream) {
    const float* x  = (const float*)d_in[0];   // [16384, 2048]
    const float* gw = (const float*)d_in[1];   // [64, 2048]
    const float* gb = (const float*)d_in[2];   // [64]

    float* out     = (float*)d_out;
    float* logits  = out;                                  // 1048576
    float* weights = out + (size_t)NTOK * NEXP;            // 32768
    float* idxf    = weights + (size_t)NTOK * 2;           // 32768
    float* mask    = idxf + (size_t)NTOK * 2;              // 2097152

    // ws layout: wh | wl (256 KB each) | partials (4 x 4 MB) | counters (512 B)
    uint4* wh = (uint4*)d_ws;
    uint4* wl = wh + 16384;
    const size_t hdrB   = 2 * 16384 * sizeof(uint4);               // 512 KB
    const size_t sliceB = (size_t)NTOK * NEXP * sizeof(float);     // 4 MB
    const size_t cntB   = 128 * sizeof(unsigned);

    if (ws_size >= hdrB + 4 * sliceB + cntB) {
        float*    part = (float*)((char*)d_ws + hdrB);
        unsigned* cnt  = (unsigned*)((char*)d_ws + hdrB + 4 * sliceB);
        prep_kernel<<<64, 256, 0, stream>>>(gw, wh, wl, cnt);
        gemm_fixup_kernel<<<dim3(128, 4), 256, 0, stream>>>(
            x, wh, wl, gb, part, cnt, logits, weights, idxf, mask);
    } else if (ws_size >= hdrB + 4 * sliceB) {
        // no counter space: proven R0 two-kernel path
        float* part = (float*)((char*)d_ws + hdrB);
        prep_kernel<<<64, 256, 0, stream>>>(gw, wh, wl, nullptr);
        gemm_kernel<512><<<dim3(128, 4), 256, 0, stream>>>(x, wh, wl, part);
        finish_kernel<<<NTGF, 256, 0, stream>>>(part, gb, logits, weights, idxf, mask, 4);
    } else {
        // tiny ws: single K-slice into logits, then finish in-place (KS=1)
        prep_kernel<<<64, 256, 0, stream>>>(gw, wh, wl, nullptr);
        gemm_kernel<2048><<<dim3(128, 1), 256, 0, stream>>>(x, wh, wl, logits);
        finish_kernel<<<NTGF, 256, 0, stream>>>(logits, gb, logits, weights, idxf, mask, 1);
    }
}